// Round 2
// baseline (174.653 us; speedup 1.0000x reference)
//
#include <hip/hip_runtime.h>
#include <hip/hip_bf16.h>

typedef _Float16 f16;
typedef _Float16 f16x8 __attribute__((ext_vector_type(8)));
typedef _Float16 f16x4 __attribute__((ext_vector_type(4)));
typedef float f32x4 __attribute__((ext_vector_type(4)));

#define PADK 40    // 32 + 8 f16 -> 80B rows: 16B aligned, conflict-free
#define PADK2 72   // 64 + 8 f16 -> 144B rows

#define W1SCALE 262144.0f              // 2^18: lifts W1 (~2e-6, f16-denormal!) to ~0.5
#define W1DESCALE 3.814697265625e-06f  // 2^-18, applied in f32 epilogue of k_dft_inv

static __device__ __forceinline__ f32x4 mfma16(f16x8 a, f16x8 b, f32x4 c) {
  return __builtin_amdgcn_mfma_f32_16x16x32_f16(a, b, c, 0, 0, 0);
}

// ---------------- S0a: twiddle tables ----------------
// FhT[k2][l] (64x2048): k2<32 -> cos(2*pi*k*l/2048), k2>=32 -> -sin(...)
// Gh[l][k2] (2048x64): irfft weights with 1/N, 2/N, imag-DC-dropped folded in.
__global__ __launch_bounds__(256) void k_tables(f16* __restrict__ FhT, f16* __restrict__ Gh) {
  int idx = blockIdx.x * 256 + threadIdx.x;  // 0..131071
  const float w = 6.28318530717958647692f / 2048.0f;
  {
    int k2 = idx >> 11, l = idx & 2047;
    int k = k2 & 31;
    float th = (float)((k * l) & 2047) * w;
    float v = (k2 < 32) ? cosf(th) : -sinf(th);
    FhT[k2 * 2048 + l] = (f16)v;
  }
  {
    int l = idx >> 6, kk = idx & 63;
    int k = kk & 31;
    float th = (float)((k * l) & 2047) * w;
    float v;
    if (kk < 32) v = ((k == 0) ? 1.0f : 2.0f) * (1.0f / 2048.0f) * cosf(th);
    else         v = (k == 0) ? 0.0f : (-2.0f / 2048.0f) * sinf(th);
    Gh[l * 64 + kk] = (f16)v;
  }
}

// ---------------- S0b: f32 -> f16 cast (Wq, Wo keep [n][k] layout) ----------------
__global__ __launch_bounds__(256) void k_cast_f16(const float* __restrict__ src,
                                                  f16* __restrict__ dst, int n4) {
  int i = blockIdx.x * 256 + threadIdx.x;
  if (i < n4) {
    float4 v = ((const float4*)src)[i];
    f16x4 o = {(f16)v.x, (f16)v.y, (f16)v.z, (f16)v.w};
    *(f16x4*)(dst + (size_t)i * 4) = o;
  }
}

// ---------------- S0c: W1[i][o][m] f32 -> W1T[m][o][i] f16, scaled by 2^18 ----------------
__global__ __launch_bounds__(256) void k_w1t(const float* __restrict__ W1r,
                                             const float* __restrict__ W1i,
                                             f16* __restrict__ W1rT,
                                             f16* __restrict__ W1iT) {
  __shared__ __align__(16) f16 WL[8192];  // [ii(8)][oo(32)][m(32)]
  const int o0 = blockIdx.x * 32, i0 = blockIdx.y * 8;
  const int t = threadIdx.x;
  for (int pass = 0; pass < 2; ++pass) {
    const float* src = pass ? W1i : W1r;
    f16* dst = pass ? W1iT : W1rT;
    __syncthreads();
    for (int r = 0; r < 32; ++r) {
      int idx = t + 256 * r;
      int m = idx & 31, oo = (idx >> 5) & 31, ii = idx >> 10;
      WL[idx] = (f16)(W1SCALE * src[(size_t)(i0 + ii) * 16384 + (o0 + oo) * 32 + m]);
    }
    __syncthreads();
    for (int wq = 0; wq < 4; ++wq) {
      int p = t + 256 * wq;  // 0..1023
      int oo = p >> 5, m = p & 31;
      f16x8 v;
      for (int ii = 0; ii < 8; ++ii) v[ii] = WL[ii * 1024 + oo * 32 + m];
      *(f16x8*)(dst + (size_t)m * 262144 + (size_t)(o0 + oo) * 512 + i0) = v;
    }
  }
}

// ---------------- S1: t[b,k2,j] = sum_l FhT[k2,l] * queries[b,l,j] ----------------
__global__ __launch_bounds__(256) void k_dft_fwd(const f16* __restrict__ FhT,
                                                 const float* __restrict__ queries,
                                                 f16* __restrict__ t16) {
  __shared__ __align__(16) f16 As[64 * PADK];  // [k2][l]
  __shared__ __align__(16) f16 Bs[64 * PADK];  // [j][l] (transposed stage)
  const int n0 = blockIdx.x * 64;
  const int b  = blockIdx.y;
  const int t = threadIdx.x;
  const int wid = t >> 6, lane = t & 63;
  const int mh = wid & 1, nh = wid >> 1;
  const int arow = t >> 2, ac8 = (t & 3) << 3;
  const int bcol = t & 63, bkg = t >> 6;
  f32x4 acc[2][2] = {};
  for (int k0 = 0; k0 < 2048; k0 += 32) {
    __syncthreads();
    *(f16x8*)(As + arow * PADK + ac8) =
        *(const f16x8*)(FhT + (size_t)arow * 2048 + k0 + ac8);
    const float* qp = queries + ((size_t)b * 2048 + k0 + bkg * 8) * 512 + n0 + bcol;
    float v[8];
#pragma unroll
    for (int r = 0; r < 8; ++r) v[r] = qp[(size_t)r * 512];
    f16x4 lo = {(f16)v[0], (f16)v[1], (f16)v[2], (f16)v[3]};
    f16x4 hi = {(f16)v[4], (f16)v[5], (f16)v[6], (f16)v[7]};
    *(f16x4*)(Bs + bcol * PADK + bkg * 8) = lo;
    *(f16x4*)(Bs + bcol * PADK + bkg * 8 + 4) = hi;
    __syncthreads();
    const int kofs = (lane >> 4) << 3;
    f16x8 a0 = *(const f16x8*)(As + (mh * 32 + 0  + (lane & 15)) * PADK + kofs);
    f16x8 a1 = *(const f16x8*)(As + (mh * 32 + 16 + (lane & 15)) * PADK + kofs);
    f16x8 b0 = *(const f16x8*)(Bs + (nh * 32 + 0  + (lane & 15)) * PADK + kofs);
    f16x8 b1 = *(const f16x8*)(Bs + (nh * 32 + 16 + (lane & 15)) * PADK + kofs);
    acc[0][0] = mfma16(a0, b0, acc[0][0]);
    acc[0][1] = mfma16(a0, b1, acc[0][1]);
    acc[1][0] = mfma16(a1, b0, acc[1][0]);
    acc[1][1] = mfma16(a1, b1, acc[1][1]);
  }
#pragma unroll
  for (int mf = 0; mf < 2; ++mf)
#pragma unroll
    for (int nf = 0; nf < 2; ++nf)
#pragma unroll
      for (int r = 0; r < 4; ++r) {
        int k2 = mh * 32 + mf * 16 + ((lane >> 4) << 2) + r;
        int col = n0 + nh * 32 + nf * 16 + (lane & 15);
        t16[((size_t)b * 64 + k2) * 512 + col] = (f16)acc[mf][nf][r];
      }
}

// ------- S2/S4: C[M][512] = A[M][512] @ Bnk^T where Bnk is [n][k] f16 -------
__global__ __launch_bounds__(256) void k_gemm_nk(const f16* __restrict__ A,
                                                 const f16* __restrict__ Bnk,
                                                 f16* __restrict__ C,
                                                 const float* __restrict__ bias0,
                                                 float bscale) {
  __shared__ __align__(16) f16 As[64 * PADK];
  __shared__ __align__(16) f16 Bs[64 * PADK];
  const int n0 = blockIdx.x * 64, m0 = blockIdx.y * 64;
  const int t = threadIdx.x;
  const int wid = t >> 6, lane = t & 63;
  const int mh = wid & 1, nh = wid >> 1;
  const int row = t >> 2, c8 = (t & 3) << 3;
  f32x4 acc[2][2] = {};
  for (int k0 = 0; k0 < 512; k0 += 32) {
    __syncthreads();
    *(f16x8*)(As + row * PADK + c8) =
        *(const f16x8*)(A + (size_t)(m0 + row) * 512 + k0 + c8);
    *(f16x8*)(Bs + row * PADK + c8) =
        *(const f16x8*)(Bnk + (size_t)(n0 + row) * 512 + k0 + c8);
    __syncthreads();
    const int kofs = (lane >> 4) << 3;
    f16x8 a0 = *(const f16x8*)(As + (mh * 32 + 0  + (lane & 15)) * PADK + kofs);
    f16x8 a1 = *(const f16x8*)(As + (mh * 32 + 16 + (lane & 15)) * PADK + kofs);
    f16x8 b0 = *(const f16x8*)(Bs + (nh * 32 + 0  + (lane & 15)) * PADK + kofs);
    f16x8 b1 = *(const f16x8*)(Bs + (nh * 32 + 16 + (lane & 15)) * PADK + kofs);
    acc[0][0] = mfma16(a0, b0, acc[0][0]);
    acc[0][1] = mfma16(a0, b1, acc[0][1]);
    acc[1][0] = mfma16(a1, b0, acc[1][0]);
    acc[1][1] = mfma16(a1, b1, acc[1][1]);
  }
#pragma unroll
  for (int mf = 0; mf < 2; ++mf)
#pragma unroll
    for (int nf = 0; nf < 2; ++nf)
#pragma unroll
      for (int r = 0; r < 4; ++r) {
        int mg = m0 + mh * 32 + mf * 16 + ((lane >> 4) << 2) + r;
        int col = n0 + nh * 32 + nf * 16 + (lane & 15);
        float cv = acc[mf][nf][r];
        if (bias0 != nullptr && (mg & 63) == 0) cv += bscale * bias0[col];
        C[(size_t)mg * 512 + col] = (f16)cv;
      }
}

// ---------------- S3: per-mode complex mix ----------------
// oselR[b,m,o] = sum_i selR*W1r - selI*W1i ; oselI = selR*W1i + selI*W1r
__global__ __launch_bounds__(256) void k_modes(const f16* __restrict__ sel,
                                               const f16* __restrict__ W1rT,
                                               const f16* __restrict__ W1iT,
                                               f16* __restrict__ osel) {
  __shared__ __align__(16) f16 ARs[32 * PADK];
  __shared__ __align__(16) f16 AIs[32 * PADK];
  __shared__ __align__(16) f16 BRs[64 * PADK];
  __shared__ __align__(16) f16 BIs[64 * PADK];
  const int n0 = blockIdx.x * 64, m = blockIdx.y;
  const int t = threadIdx.x, wid = t >> 6, lane = t & 63;
  const int mh = wid & 1, nh = wid >> 1;
  const int brow = t >> 2, bc8 = (t & 3) << 3;
  const f16* Wr = W1rT + (size_t)m * 262144;
  const f16* Wi = W1iT + (size_t)m * 262144;
  f32x4 accR[2] = {}, accI[2] = {};
  for (int k0 = 0; k0 < 512; k0 += 32) {
    __syncthreads();
    if (t < 128) {
      int row = t >> 2, c8 = (t & 3) << 3;
      *(f16x8*)(ARs + row * PADK + c8) =
          *(const f16x8*)(sel + ((size_t)row * 64 + m) * 512 + k0 + c8);
    } else {
      int tt = t - 128, row = tt >> 2, c8 = (tt & 3) << 3;
      *(f16x8*)(AIs + row * PADK + c8) =
          *(const f16x8*)(sel + ((size_t)row * 64 + 32 + m) * 512 + k0 + c8);
    }
    *(f16x8*)(BRs + brow * PADK + bc8) =
        *(const f16x8*)(Wr + (size_t)(n0 + brow) * 512 + k0 + bc8);
    *(f16x8*)(BIs + brow * PADK + bc8) =
        *(const f16x8*)(Wi + (size_t)(n0 + brow) * 512 + k0 + bc8);
    __syncthreads();
    const int kofs = (lane >> 4) << 3;
    f16x8 ar = *(const f16x8*)(ARs + (mh * 16 + (lane & 15)) * PADK + kofs);
    f16x8 ai = *(const f16x8*)(AIs + (mh * 16 + (lane & 15)) * PADK + kofs);
    f16x8 ain = -ai;
#pragma unroll
    for (int nf = 0; nf < 2; ++nf) {
      f16x8 br = *(const f16x8*)(BRs + (nh * 32 + nf * 16 + (lane & 15)) * PADK + kofs);
      f16x8 bi = *(const f16x8*)(BIs + (nh * 32 + nf * 16 + (lane & 15)) * PADK + kofs);
      accR[nf] = mfma16(ar, br, accR[nf]);
      accR[nf] = mfma16(ain, bi, accR[nf]);
      accI[nf] = mfma16(ar, bi, accI[nf]);
      accI[nf] = mfma16(ai, br, accI[nf]);
    }
  }
#pragma unroll
  for (int nf = 0; nf < 2; ++nf)
#pragma unroll
    for (int r = 0; r < 4; ++r) {
      int bb = mh * 16 + ((lane >> 4) << 2) + r;  // batch index 0..31
      int col = n0 + nh * 32 + nf * 16 + (lane & 15);
      osel[((size_t)bb * 64 + m) * 512 + col] = (f16)accR[nf][r];
      osel[((size_t)bb * 64 + 32 + m) * 512 + col] = (f16)accI[nf][r];
    }
}

// ---------------- S5: out[b,l,o] = (sum_k2 Gh[l,k2]*u[b,k2,o]) * 2^-18 + bo[o] ----------------
__global__ __launch_bounds__(256) void k_dft_inv(const f16* __restrict__ Gh,
                                                 const f16* __restrict__ u,
                                                 const float* __restrict__ bo,
                                                 float* __restrict__ out) {
  __shared__ __align__(16) f16 As[64 * PADK2];  // [l][k2]
  __shared__ __align__(16) f16 Bs[64 * PADK2];  // [o][k2] transposed stage
  const int n0 = blockIdx.x * 64, l0 = blockIdx.y * 64, b = blockIdx.z;
  const int t = threadIdx.x, wid = t >> 6, lane = t & 63;
  const int mh = wid & 1, nh = wid >> 1;
#pragma unroll
  for (int p = 0; p < 2; ++p) {
    int v = t + 256 * p, row = v >> 3, c8 = (v & 7) << 3;
    *(f16x8*)(As + row * PADK2 + c8) = *(const f16x8*)(Gh + (size_t)(l0 + row) * 64 + c8);
  }
  {
    int col = t & 63, kg = t >> 6;
    const f16* up = u + ((size_t)b * 64 + kg * 16) * 512 + n0 + col;
    f16 vv[16];
#pragma unroll
    for (int s = 0; s < 16; ++s) vv[s] = up[(size_t)s * 512];
#pragma unroll
    for (int s4 = 0; s4 < 4; ++s4) {
      f16x4 pk = {vv[s4 * 4], vv[s4 * 4 + 1], vv[s4 * 4 + 2], vv[s4 * 4 + 3]};
      *(f16x4*)(Bs + col * PADK2 + kg * 16 + s4 * 4) = pk;
    }
  }
  __syncthreads();
  f32x4 acc[2][2] = {};
#pragma unroll
  for (int ks = 0; ks < 2; ++ks) {
    const int kofs = ks * 32 + ((lane >> 4) << 3);
    f16x8 a0 = *(const f16x8*)(As + (mh * 32 + 0  + (lane & 15)) * PADK2 + kofs);
    f16x8 a1 = *(const f16x8*)(As + (mh * 32 + 16 + (lane & 15)) * PADK2 + kofs);
    f16x8 b0 = *(const f16x8*)(Bs + (nh * 32 + 0  + (lane & 15)) * PADK2 + kofs);
    f16x8 b1 = *(const f16x8*)(Bs + (nh * 32 + 16 + (lane & 15)) * PADK2 + kofs);
    acc[0][0] = mfma16(a0, b0, acc[0][0]);
    acc[0][1] = mfma16(a0, b1, acc[0][1]);
    acc[1][0] = mfma16(a1, b0, acc[1][0]);
    acc[1][1] = mfma16(a1, b1, acc[1][1]);
  }
#pragma unroll
  for (int mf = 0; mf < 2; ++mf)
#pragma unroll
    for (int nf = 0; nf < 2; ++nf)
#pragma unroll
      for (int r = 0; r < 4; ++r) {
        int l = l0 + mh * 32 + mf * 16 + ((lane >> 4) << 2) + r;
        int col = n0 + nh * 32 + nf * 16 + (lane & 15);
        float cv = acc[mf][nf][r] * W1DESCALE + bo[col];
        out[((size_t)b * 2048 + l) * 512 + col] = cv;
      }
}

extern "C" void kernel_launch(void* const* d_in, const int* in_sizes, int n_in,
                              void* d_out, int out_size, void* d_ws, size_t ws_size,
                              hipStream_t stream) {
  const float* queries = (const float*)d_in[0];
  const float* Wq      = (const float*)d_in[1];
  const float* bq      = (const float*)d_in[2];
  const float* W1r     = (const float*)d_in[3];
  const float* W1i     = (const float*)d_in[4];
  const float* Wo      = (const float*)d_in[5];
  const float* bo      = (const float*)d_in[6];
  float* out           = (float*)d_out;   // reference output dtype is float32

  char* ws = (char*)d_ws;
  size_t off = 0;
  auto alloc = [&](size_t bytes) {
    off = (off + 255) & ~(size_t)255;
    char* p = ws + off;
    off += bytes;
    return p;
  };
  f16* FhT  = (f16*)alloc((size_t)64 * 2048 * 2);
  f16* Gh   = (f16*)alloc((size_t)2048 * 64 * 2);
  f16* Wq16 = (f16*)alloc((size_t)512 * 512 * 2);
  f16* Wo16 = (f16*)alloc((size_t)512 * 512 * 2);
  f16* W1rT = (f16*)alloc((size_t)32 * 512 * 512 * 2);
  f16* W1iT = (f16*)alloc((size_t)32 * 512 * 512 * 2);
  f16* t16  = (f16*)alloc((size_t)2048 * 512 * 2);
  f16* sel  = (f16*)alloc((size_t)2048 * 512 * 2);
  f16* osel = (f16*)alloc((size_t)2048 * 512 * 2);
  f16* u16  = (f16*)alloc((size_t)2048 * 512 * 2);

  hipLaunchKernelGGL(k_tables, dim3(512), dim3(256), 0, stream, FhT, Gh);
  hipLaunchKernelGGL(k_cast_f16, dim3(256), dim3(256), 0, stream, Wq, Wq16, 65536);
  hipLaunchKernelGGL(k_cast_f16, dim3(256), dim3(256), 0, stream, Wo, Wo16, 65536);
  hipLaunchKernelGGL(k_w1t, dim3(16, 64), dim3(256), 0, stream, W1r, W1i, W1rT, W1iT);
  hipLaunchKernelGGL(k_dft_fwd, dim3(8, 32), dim3(256), 0, stream, FhT, queries, t16);
  hipLaunchKernelGGL(k_gemm_nk, dim3(8, 32), dim3(256), 0, stream, t16, Wq16, sel, bq, 2048.0f);
  hipLaunchKernelGGL(k_modes, dim3(8, 32), dim3(256), 0, stream, sel, W1rT, W1iT, osel);
  hipLaunchKernelGGL(k_gemm_nk, dim3(8, 32), dim3(256), 0, stream, osel, Wo16, u16,
                     (const float*)nullptr, 0.0f);
  hipLaunchKernelGGL(k_dft_inv, dim3(8, 32, 32), dim3(256), 0, stream, Gh, u16, bo, out);
}

// Round 3
// 146.631 us; speedup vs baseline: 1.1911x; 1.1911x over previous
//
#include <hip/hip_runtime.h>
#include <hip/hip_bf16.h>

typedef _Float16 f16;
typedef _Float16 f16x8 __attribute__((ext_vector_type(8)));
typedef _Float16 f16x4 __attribute__((ext_vector_type(4)));
typedef float f32x4 __attribute__((ext_vector_type(4)));

#define PADK 40    // 32 + 8 f16 -> 80B rows: 16B aligned, conflict-free
#define PADK2 72   // 64 + 8 f16 -> 144B rows

#define W1SCALE 262144.0f              // 2^18: lifts W1 (~2e-6, f16-denormal!) to ~0.5
#define W1DESCALE 3.814697265625e-06f  // 2^-18, applied in f32 epilogue of k_dft_inv

static __device__ __forceinline__ f32x4 mfma16(f16x8 a, f16x8 b, f32x4 c) {
  return __builtin_amdgcn_mfma_f32_16x16x32_f16(a, b, c, 0, 0, 0);
}

// ---------------- S0a: twiddle tables ----------------
__global__ __launch_bounds__(256) void k_tables(f16* __restrict__ FhT, f16* __restrict__ Gh) {
  int idx = blockIdx.x * 256 + threadIdx.x;  // 0..131071
  const float w = 6.28318530717958647692f / 2048.0f;
  {
    int k2 = idx >> 11, l = idx & 2047;
    int k = k2 & 31;
    float th = (float)((k * l) & 2047) * w;
    float v = (k2 < 32) ? cosf(th) : -sinf(th);
    FhT[k2 * 2048 + l] = (f16)v;
  }
  {
    int l = idx >> 6, kk = idx & 63;
    int k = kk & 31;
    float th = (float)((k * l) & 2047) * w;
    float v;
    if (kk < 32) v = ((k == 0) ? 1.0f : 2.0f) * (1.0f / 2048.0f) * cosf(th);
    else         v = (k == 0) ? 0.0f : (-2.0f / 2048.0f) * sinf(th);
    Gh[l * 64 + kk] = (f16)v;
  }
}

// ---------------- S0b: f32 -> f16 cast ----------------
__global__ __launch_bounds__(256) void k_cast_f16(const float* __restrict__ src,
                                                  f16* __restrict__ dst, int n4) {
  int i = blockIdx.x * 256 + threadIdx.x;
  if (i < n4) {
    float4 v = ((const float4*)src)[i];
    f16x4 o = {(f16)v.x, (f16)v.y, (f16)v.z, (f16)v.w};
    *(f16x4*)(dst + (size_t)i * 4) = o;
  }
}

// ---------------- S0c: W1[i][o][m] f32 -> W1T[m][o][i] f16 (scaled) ----------------
// Block covers i-span 64 (full 128B output runs), o-span 8, all 32 m.
__global__ __launch_bounds__(256) void k_w1t2(const float* __restrict__ W1r,
                                              const float* __restrict__ W1i,
                                              f16* __restrict__ W1rT,
                                              f16* __restrict__ W1iT) {
  __shared__ __align__(16) f16 WL[256 * 72];  // [(oo*32+m)][ii(64) pad 72]
  const int o0 = blockIdx.x * 8, i0 = blockIdx.y * 64;
  const int t = threadIdx.x;
  for (int pass = 0; pass < 2; ++pass) {
    const float* src = pass ? W1i : W1r;
    f16* dst = pass ? W1iT : W1rT;
    __syncthreads();
#pragma unroll
    for (int j = 0; j < 16; ++j) {
      int idx = t + 256 * j;            // 0..4095
      int mq = idx & 7, oo = (idx >> 3) & 7, ii = idx >> 6;
      const float4 v = *(const float4*)(src + (size_t)(i0 + ii) * 16384 + (o0 + oo) * 32 + mq * 4);
      WL[(oo * 32 + mq * 4 + 0) * 72 + ii] = (f16)(W1SCALE * v.x);
      WL[(oo * 32 + mq * 4 + 1) * 72 + ii] = (f16)(W1SCALE * v.y);
      WL[(oo * 32 + mq * 4 + 2) * 72 + ii] = (f16)(W1SCALE * v.z);
      WL[(oo * 32 + mq * 4 + 3) * 72 + ii] = (f16)(W1SCALE * v.w);
    }
    __syncthreads();
#pragma unroll
    for (int j = 0; j < 8; ++j) {
      int idx = t + 256 * j;            // 0..2047
      int i8 = idx & 7, m = (idx >> 3) & 31, oo = idx >> 8;
      f16x8 v = *(const f16x8*)(&WL[(oo * 32 + m) * 72 + i8 * 8]);
      *(f16x8*)(dst + (size_t)m * 262144 + (size_t)(o0 + oo) * 512 + i0 + i8 * 8) = v;
    }
  }
}

// ---------------- S1: split-K forward DFT ----------------
// partial[c][b*64+k2][col] = sum_{l in chunk c} FhT[k2,l] * queries[b,l,col]
__global__ __launch_bounds__(256) void k_dft_fwd(const f16* __restrict__ FhT,
                                                 const float* __restrict__ queries,
                                                 float* __restrict__ p32) {
  __shared__ __align__(16) f16 As[64 * PADK];  // [k2][l]
  __shared__ __align__(16) f16 Bs[64 * PADK];  // [j][l]
  const int n0 = blockIdx.x * 64;
  const int b  = blockIdx.y;
  const int kb = blockIdx.z * 256;
  const int t = threadIdx.x;
  const int wid = t >> 6, lane = t & 63;
  const int mh = wid & 1, nh = wid >> 1;
  const int arow = t >> 2, ac8 = (t & 3) << 3;
  const int bcol = t & 63, bkg = t >> 6;
  f32x4 acc[2][2] = {};
  for (int k0 = kb; k0 < kb + 256; k0 += 32) {
    __syncthreads();
    *(f16x8*)(As + arow * PADK + ac8) =
        *(const f16x8*)(FhT + (size_t)arow * 2048 + k0 + ac8);
    const float* qp = queries + ((size_t)b * 2048 + k0 + bkg * 8) * 512 + n0 + bcol;
    float v[8];
#pragma unroll
    for (int r = 0; r < 8; ++r) v[r] = qp[(size_t)r * 512];
    f16x4 lo = {(f16)v[0], (f16)v[1], (f16)v[2], (f16)v[3]};
    f16x4 hi = {(f16)v[4], (f16)v[5], (f16)v[6], (f16)v[7]};
    *(f16x4*)(Bs + bcol * PADK + bkg * 8) = lo;
    *(f16x4*)(Bs + bcol * PADK + bkg * 8 + 4) = hi;
    __syncthreads();
    const int kofs = (lane >> 4) << 3;
    f16x8 a0 = *(const f16x8*)(As + (mh * 32 + 0  + (lane & 15)) * PADK + kofs);
    f16x8 a1 = *(const f16x8*)(As + (mh * 32 + 16 + (lane & 15)) * PADK + kofs);
    f16x8 b0 = *(const f16x8*)(Bs + (nh * 32 + 0  + (lane & 15)) * PADK + kofs);
    f16x8 b1 = *(const f16x8*)(Bs + (nh * 32 + 16 + (lane & 15)) * PADK + kofs);
    acc[0][0] = mfma16(a0, b0, acc[0][0]);
    acc[0][1] = mfma16(a0, b1, acc[0][1]);
    acc[1][0] = mfma16(a1, b0, acc[1][0]);
    acc[1][1] = mfma16(a1, b1, acc[1][1]);
  }
#pragma unroll
  for (int mf = 0; mf < 2; ++mf)
#pragma unroll
    for (int nf = 0; nf < 2; ++nf)
#pragma unroll
      for (int r = 0; r < 4; ++r) {
        int k2 = mh * 32 + mf * 16 + ((lane >> 4) << 2) + r;
        int col = n0 + nh * 32 + nf * 16 + (lane & 15);
        p32[((size_t)blockIdx.z * 2048 + b * 64 + k2) * 512 + col] = acc[mf][nf][r];
      }
}

// ---------------- S1b: reduce 8 partials -> t16 ----------------
__global__ __launch_bounds__(256) void k_reduce8(const float* __restrict__ p,
                                                 f16* __restrict__ dst) {
  size_t i4 = (size_t)blockIdx.x * 256 + threadIdx.x;  // float4 index, 262144 total
  float4 s = {0.f, 0.f, 0.f, 0.f};
#pragma unroll
  for (int c = 0; c < 8; ++c) {
    float4 v = ((const float4*)p)[(size_t)c * 262144 + i4];
    s.x += v.x; s.y += v.y; s.z += v.z; s.w += v.w;
  }
  f16x4 o = {(f16)s.x, (f16)s.y, (f16)s.z, (f16)s.w};
  *(f16x4*)(dst + i4 * 4) = o;
}

// ------- S2/S4: C[M][512] = A[M][512] @ Bnk^T, 64M x 32N tiles -------
__global__ __launch_bounds__(256) void k_gemm_nk(const f16* __restrict__ A,
                                                 const f16* __restrict__ Bnk,
                                                 f16* __restrict__ C,
                                                 const float* __restrict__ bias0,
                                                 float bscale) {
  __shared__ __align__(16) f16 As[64 * PADK];
  __shared__ __align__(16) f16 Bs[32 * PADK];
  const int n0 = blockIdx.x * 32, m0 = blockIdx.y * 64;
  const int t = threadIdx.x;
  const int wid = t >> 6, lane = t & 63;
  const int mh = wid & 1, nh = wid >> 1;
  const int row = t >> 2, c8 = (t & 3) << 3;
  f32x4 acc[2] = {};
  for (int k0 = 0; k0 < 512; k0 += 32) {
    __syncthreads();
    *(f16x8*)(As + row * PADK + c8) =
        *(const f16x8*)(A + (size_t)(m0 + row) * 512 + k0 + c8);
    if (t < 128)
      *(f16x8*)(Bs + row * PADK + c8) =
          *(const f16x8*)(Bnk + (size_t)(n0 + row) * 512 + k0 + c8);
    __syncthreads();
    const int kofs = (lane >> 4) << 3;
    f16x8 a0 = *(const f16x8*)(As + (mh * 32 + 0  + (lane & 15)) * PADK + kofs);
    f16x8 a1 = *(const f16x8*)(As + (mh * 32 + 16 + (lane & 15)) * PADK + kofs);
    f16x8 b0 = *(const f16x8*)(Bs + (nh * 16 + (lane & 15)) * PADK + kofs);
    acc[0] = mfma16(a0, b0, acc[0]);
    acc[1] = mfma16(a1, b0, acc[1]);
  }
#pragma unroll
  for (int mf = 0; mf < 2; ++mf)
#pragma unroll
    for (int r = 0; r < 4; ++r) {
      int mg = m0 + mh * 32 + mf * 16 + ((lane >> 4) << 2) + r;
      int col = n0 + nh * 16 + (lane & 15);
      float cv = acc[mf][r];
      if (bias0 != nullptr && (mg & 63) == 0) cv += bscale * bias0[col];
      C[(size_t)mg * 512 + col] = (f16)cv;
    }
}

// ---------------- S3: per-mode complex mix, 32N tiles ----------------
__global__ __launch_bounds__(256) void k_modes(const f16* __restrict__ sel,
                                               const f16* __restrict__ W1rT,
                                               const f16* __restrict__ W1iT,
                                               f16* __restrict__ osel) {
  __shared__ __align__(16) f16 ARs[32 * PADK];
  __shared__ __align__(16) f16 AIs[32 * PADK];
  __shared__ __align__(16) f16 BRs[32 * PADK];
  __shared__ __align__(16) f16 BIs[32 * PADK];
  const int n0 = blockIdx.x * 32, m = blockIdx.y;
  const int t = threadIdx.x, wid = t >> 6, lane = t & 63;
  const int mh = wid & 1, nh = wid >> 1;
  const f16* Wr = W1rT + (size_t)m * 262144;
  const f16* Wi = W1iT + (size_t)m * 262144;
  const int srow = lane >> 1, sc0 = (lane & 1) << 3;  // stage: row 0..31, col chunk
  f32x4 accR, accI;
#pragma unroll
  for (int r = 0; r < 4; ++r) { accR[r] = 0.f; accI[r] = 0.f; }
  for (int k0 = 0; k0 < 512; k0 += 32) {
    __syncthreads();
    // wave w stages buffer w: 32 rows x 32 cols, 2 x f16x8 per lane
    if (wid == 0) {
      *(f16x8*)(ARs + srow * PADK + sc0) =
          *(const f16x8*)(sel + ((size_t)srow * 64 + m) * 512 + k0 + sc0);
      *(f16x8*)(ARs + srow * PADK + sc0 + 16) =
          *(const f16x8*)(sel + ((size_t)srow * 64 + m) * 512 + k0 + sc0 + 16);
    } else if (wid == 1) {
      *(f16x8*)(AIs + srow * PADK + sc0) =
          *(const f16x8*)(sel + ((size_t)srow * 64 + 32 + m) * 512 + k0 + sc0);
      *(f16x8*)(AIs + srow * PADK + sc0 + 16) =
          *(const f16x8*)(sel + ((size_t)srow * 64 + 32 + m) * 512 + k0 + sc0 + 16);
    } else if (wid == 2) {
      *(f16x8*)(BRs + srow * PADK + sc0) =
          *(const f16x8*)(Wr + (size_t)(n0 + srow) * 512 + k0 + sc0);
      *(f16x8*)(BRs + srow * PADK + sc0 + 16) =
          *(const f16x8*)(Wr + (size_t)(n0 + srow) * 512 + k0 + sc0 + 16);
    } else {
      *(f16x8*)(BIs + srow * PADK + sc0) =
          *(const f16x8*)(Wi + (size_t)(n0 + srow) * 512 + k0 + sc0);
      *(f16x8*)(BIs + srow * PADK + sc0 + 16) =
          *(const f16x8*)(Wi + (size_t)(n0 + srow) * 512 + k0 + sc0 + 16);
    }
    __syncthreads();
    const int kofs = (lane >> 4) << 3;
    f16x8 ar = *(const f16x8*)(ARs + (mh * 16 + (lane & 15)) * PADK + kofs);
    f16x8 ai = *(const f16x8*)(AIs + (mh * 16 + (lane & 15)) * PADK + kofs);
    f16x8 ain = -ai;
    f16x8 br = *(const f16x8*)(BRs + (nh * 16 + (lane & 15)) * PADK + kofs);
    f16x8 bi = *(const f16x8*)(BIs + (nh * 16 + (lane & 15)) * PADK + kofs);
    accR = mfma16(ar, br, accR);
    accR = mfma16(ain, bi, accR);
    accI = mfma16(ar, bi, accI);
    accI = mfma16(ai, br, accI);
  }
#pragma unroll
  for (int r = 0; r < 4; ++r) {
    int bb = mh * 16 + ((lane >> 4) << 2) + r;  // batch 0..31
    int col = n0 + nh * 16 + (lane & 15);
    osel[((size_t)bb * 64 + m) * 512 + col] = (f16)accR[r];
    osel[((size_t)bb * 64 + 32 + m) * 512 + col] = (f16)accI[r];
  }
}

// ---------------- S5: out[b,l,o] = (sum_k2 Gh[l,k2]*u[b,k2,o]) * 2^-18 + bo[o] ----------------
__global__ __launch_bounds__(256) void k_dft_inv(const f16* __restrict__ Gh,
                                                 const f16* __restrict__ u,
                                                 const float* __restrict__ bo,
                                                 float* __restrict__ out) {
  __shared__ __align__(16) f16 As[64 * PADK2];  // [l][k2]
  __shared__ __align__(16) f16 Bs[64 * PADK2];  // [o][k2]
  const int n0 = blockIdx.x * 64, l0 = blockIdx.y * 64, b = blockIdx.z;
  const int t = threadIdx.x, wid = t >> 6, lane = t & 63;
  const int mh = wid & 1, nh = wid >> 1;
#pragma unroll
  for (int p = 0; p < 2; ++p) {
    int v = t + 256 * p, row = v >> 3, c8 = (v & 7) << 3;
    *(f16x8*)(As + row * PADK2 + c8) = *(const f16x8*)(Gh + (size_t)(l0 + row) * 64 + c8);
  }
  {
    int col = t & 63, kg = t >> 6;
    const f16* up = u + ((size_t)b * 64 + kg * 16) * 512 + n0 + col;
    f16 vv[16];
#pragma unroll
    for (int s = 0; s < 16; ++s) vv[s] = up[(size_t)s * 512];
#pragma unroll
    for (int s4 = 0; s4 < 4; ++s4) {
      f16x4 pk = {vv[s4 * 4], vv[s4 * 4 + 1], vv[s4 * 4 + 2], vv[s4 * 4 + 3]};
      *(f16x4*)(Bs + col * PADK2 + kg * 16 + s4 * 4) = pk;
    }
  }
  __syncthreads();
  f32x4 acc[2][2] = {};
#pragma unroll
  for (int ks = 0; ks < 2; ++ks) {
    const int kofs = ks * 32 + ((lane >> 4) << 3);
    f16x8 a0 = *(const f16x8*)(As + (mh * 32 + 0  + (lane & 15)) * PADK2 + kofs);
    f16x8 a1 = *(const f16x8*)(As + (mh * 32 + 16 + (lane & 15)) * PADK2 + kofs);
    f16x8 b0 = *(const f16x8*)(Bs + (nh * 32 + 0  + (lane & 15)) * PADK2 + kofs);
    f16x8 b1 = *(const f16x8*)(Bs + (nh * 32 + 16 + (lane & 15)) * PADK2 + kofs);
    acc[0][0] = mfma16(a0, b0, acc[0][0]);
    acc[0][1] = mfma16(a0, b1, acc[0][1]);
    acc[1][0] = mfma16(a1, b0, acc[1][0]);
    acc[1][1] = mfma16(a1, b1, acc[1][1]);
  }
#pragma unroll
  for (int mf = 0; mf < 2; ++mf)
#pragma unroll
    for (int nf = 0; nf < 2; ++nf)
#pragma unroll
      for (int r = 0; r < 4; ++r) {
        int l = l0 + mh * 32 + mf * 16 + ((lane >> 4) << 2) + r;
        int col = n0 + nh * 32 + nf * 16 + (lane & 15);
        float cv = acc[mf][nf][r] * W1DESCALE + bo[col];
        out[((size_t)b * 2048 + l) * 512 + col] = cv;
      }
}

extern "C" void kernel_launch(void* const* d_in, const int* in_sizes, int n_in,
                              void* d_out, int out_size, void* d_ws, size_t ws_size,
                              hipStream_t stream) {
  const float* queries = (const float*)d_in[0];
  const float* Wq      = (const float*)d_in[1];
  const float* bq      = (const float*)d_in[2];
  const float* W1r     = (const float*)d_in[3];
  const float* W1i     = (const float*)d_in[4];
  const float* Wo      = (const float*)d_in[5];
  const float* bo      = (const float*)d_in[6];
  float* out           = (float*)d_out;

  char* ws = (char*)d_ws;
  size_t off = 0;
  auto alloc = [&](size_t bytes) {
    off = (off + 255) & ~(size_t)255;
    char* p = ws + off;
    off += bytes;
    return p;
  };
  f16* FhT   = (f16*)alloc((size_t)64 * 2048 * 2);
  f16* Gh    = (f16*)alloc((size_t)2048 * 64 * 2);
  f16* Wq16  = (f16*)alloc((size_t)512 * 512 * 2);
  f16* Wo16  = (f16*)alloc((size_t)512 * 512 * 2);
  f16* W1rT  = (f16*)alloc((size_t)32 * 512 * 512 * 2);
  f16* W1iT  = (f16*)alloc((size_t)32 * 512 * 512 * 2);
  f16* t16   = (f16*)alloc((size_t)2048 * 512 * 2);
  f16* sel   = (f16*)alloc((size_t)2048 * 512 * 2);
  f16* osel  = (f16*)alloc((size_t)2048 * 512 * 2);
  f16* u16   = (f16*)alloc((size_t)2048 * 512 * 2);
  float* p32 = (float*)alloc((size_t)8 * 2048 * 512 * 4);  // split-K partials

  hipLaunchKernelGGL(k_tables, dim3(512), dim3(256), 0, stream, FhT, Gh);
  hipLaunchKernelGGL(k_cast_f16, dim3(256), dim3(256), 0, stream, Wq, Wq16, 65536);
  hipLaunchKernelGGL(k_cast_f16, dim3(256), dim3(256), 0, stream, Wo, Wo16, 65536);
  hipLaunchKernelGGL(k_w1t2, dim3(64, 8), dim3(256), 0, stream, W1r, W1i, W1rT, W1iT);
  hipLaunchKernelGGL(k_dft_fwd, dim3(8, 32, 8), dim3(256), 0, stream, FhT, queries, p32);
  hipLaunchKernelGGL(k_reduce8, dim3(1024), dim3(256), 0, stream, p32, t16);
  hipLaunchKernelGGL(k_gemm_nk, dim3(16, 32), dim3(256), 0, stream, t16, Wq16, sel, bq, 2048.0f);
  hipLaunchKernelGGL(k_modes, dim3(16, 32), dim3(256), 0, stream, sel, W1rT, W1iT, osel);
  hipLaunchKernelGGL(k_gemm_nk, dim3(16, 32), dim3(256), 0, stream, osel, Wo16, u16,
                     (const float*)nullptr, 0.0f);
  hipLaunchKernelGGL(k_dft_inv, dim3(8, 32, 32), dim3(256), 0, stream, Gh, u16, bo, out);
}